// Round 8
// baseline (613.417 us; speedup 1.0000x reference)
//
#include <hip/hip_runtime.h>
#include <hip/hip_fp16.h>

#define NN 100000
#define NE 1600000
#define SCAN_BLK 1024
#define NBLK ((NN + SCAN_BLK - 1) / SCAN_BLK)   // 98

#define EB 3072                                  // edges per bucket-block chunk
#define NBE ((NE + EB - 1) / EB)                 // 521
#define BSH 10                                   // 1024-node buckets
#define NBUCK ((NN + 1023) >> BSH)               // 98
#define BCAP 18432                               // pairs cap/bucket (exp 16327, sd ~127)

// ---------------- structure precompute ----------------

__global__ void k_init(int* __restrict__ bcur) {
    int i = blockIdx.x * blockDim.x + threadIdx.x;
    if (i < NBUCK) bcur[i] = i * BCAP;
}

// chunk edges -> per-bucket contiguous runs of (dst,src) pairs
__global__ __launch_bounds__(256) void k_bucket(
    const int* __restrict__ ei, int* __restrict__ bcur,
    long long* __restrict__ pairs, int nE) {
    __shared__ int cnt[NBUCK];
    __shared__ int sc[NBUCK];
    __shared__ int rc[NBUCK];
    __shared__ int gbase[NBUCK];
    __shared__ int tmp[256];
    __shared__ long long st[EB];

    int base = blockIdx.x * EB;
    int lim = nE - base; if (lim > EB) lim = EB;
    int tid = threadIdx.x;

    for (int i = tid; i < NBUCK; i += 256) cnt[i] = 0;
    __syncthreads();
    for (int i = tid; i < lim; i += 256) {
        int d = ei[nE + base + i];
        atomicAdd(&cnt[d >> BSH], 1);
    }
    __syncthreads();
    {
        int v = (tid < NBUCK) ? cnt[tid] : 0;
        tmp[tid] = v;
        __syncthreads();
        for (int off = 1; off < 256; off <<= 1) {
            int add = (tid >= off) ? tmp[tid - off] : 0;
            __syncthreads();
            tmp[tid] += add;
            __syncthreads();
        }
        if (tid < NBUCK) {
            int e = tmp[tid] - v;
            sc[tid] = e;
            rc[tid] = e;
            gbase[tid] = (v > 0) ? atomicAdd(&bcur[tid], v) : 0;
        }
    }
    __syncthreads();
    for (int i = tid; i < lim; i += 256) {
        int s = ei[base + i];
        int d = ei[nE + base + i];
        int p = atomicAdd(&rc[d >> BSH], 1);
        st[p] = ((long long)d << 32) | (unsigned int)s;
    }
    __syncthreads();
    for (int i = tid; i < lim; i += 256) {
        long long pr = st[i];
        int b = (int)(pr >> 32) >> BSH;
        pairs[gbase[b] + (i - sc[b])] = pr;
    }
}

// per-bucket LDS histogram -> coalesced non-atomic deg write
__global__ __launch_bounds__(256) void k_count2(
    const long long* __restrict__ pairs, const int* __restrict__ bcur,
    int* __restrict__ deg) {
    __shared__ int cnt[1 << BSH];
    int b = blockIdx.x;
    int gb = b * BCAP;
    int m = bcur[b] - gb;
    for (int i = threadIdx.x; i < (1 << BSH); i += 256) cnt[i] = 0;
    __syncthreads();
    for (int i = threadIdx.x; i < m; i += 256) {
        int d = (int)(pairs[gb + i] >> 32);
        atomicAdd(&cnt[d & ((1 << BSH) - 1)], 1);
    }
    __syncthreads();
    int base = b << BSH;
    for (int i = threadIdx.x; i < (1 << BSH); i += 256) {
        int v = base + i;
        if (v < NN) deg[v] = cnt[i];
    }
}

__global__ __launch_bounds__(SCAN_BLK) void k_scan1(
    const int* __restrict__ deg, int* __restrict__ exc, int* __restrict__ bsum, int n) {
    __shared__ int sh[SCAN_BLK];
    int tid = threadIdx.x;
    int i = blockIdx.x * SCAN_BLK + tid;
    int v = (i < n) ? deg[i] : 0;
    sh[tid] = v;
    __syncthreads();
    for (int off = 1; off < SCAN_BLK; off <<= 1) {
        int add = (tid >= off) ? sh[tid - off] : 0;
        __syncthreads();
        sh[tid] += add;
        __syncthreads();
    }
    if (i < n) exc[i] = sh[tid] - v;
    if (tid == SCAN_BLK - 1) bsum[blockIdx.x] = sh[tid];
}

__global__ __launch_bounds__(128) void k_scan2(int* __restrict__ bsum, int nb) {
    __shared__ int sh[128];
    int tid = threadIdx.x;
    int v = (tid < nb) ? bsum[tid] : 0;
    sh[tid] = v;
    __syncthreads();
    for (int off = 1; off < 128; off <<= 1) {
        int add = (tid >= off) ? sh[tid - off] : 0;
        __syncthreads();
        sh[tid] += add;
        __syncthreads();
    }
    if (tid < nb) bsum[tid] = sh[tid] - v;  // exclusive
}

// rowptr + dinv + hd0 = x*dinv (fp16)
__global__ __launch_bounds__(SCAN_BLK) void k_scan3(
    const int* __restrict__ exc, const int* __restrict__ bsum,
    const int* __restrict__ deg, const float* __restrict__ x,
    int* __restrict__ rowptr, float* __restrict__ dinv,
    __half2* __restrict__ hd0, int n) {
    int i = blockIdx.x * SCAN_BLK + threadIdx.x;
    if (i >= n) return;
    rowptr[i] = exc[i] + bsum[blockIdx.x];
    float dv = rsqrtf((float)(deg[i] + 1));  // +1 = self loop
    dinv[i] = dv;
    hd0[i] = __floats2half2_rn(x[2 * i] * dv, x[2 * i + 1] * dv);
    if (i == 0) rowptr[n] = NE;
}

// per-bucket scatter with LDS cursors; csr writes confined to bucket window
__global__ __launch_bounds__(256) void k_fill3(
    const long long* __restrict__ pairs, const int* __restrict__ bcur,
    const int* __restrict__ rowptr, int* __restrict__ csr_src) {
    __shared__ int lcur[1 << BSH];
    int b = blockIdx.x;
    int gb = b * BCAP;
    int m = bcur[b] - gb;
    int base = b << BSH;
    for (int i = threadIdx.x; i < (1 << BSH); i += 256) {
        int v = base + i;
        lcur[i] = (v < NN) ? rowptr[v] : 0;
    }
    __syncthreads();
    for (int i = threadIdx.x; i < m; i += 256) {
        long long pr = pairs[gb + i];
        int d = (int)(pr >> 32);
        int s = (int)(pr & 0xffffffffLL);
        int pos = atomicAdd(&lcur[d & ((1 << BSH) - 1)], 1);
        csr_src[pos] = s;
    }
}

// ---------------- layer kernels ----------------
// agg[v] = dinv[v] * (sum_j hd_in[src_j] + hd_in[v]) ; o = agg@W + b
// hd_out = relu(o)*dinv (fp16)   |  LAST: out = o + xorig (fp32)

// L1: DIN=2, half2 rows; 16-lane edge-split + butterfly.
__global__ __launch_bounds__(256) void k_layer1(
    const int* __restrict__ rowptr, const int* __restrict__ csr_src,
    const __half2* __restrict__ hd0, const float* __restrict__ Wg,
    const float* __restrict__ bg, const float* __restrict__ dinv,
    __half* __restrict__ hd1, int n) {
    __shared__ float sW[32];
    if (threadIdx.x < 32) sW[threadIdx.x] = Wg[threadIdx.x];
    __syncthreads();
    int v = blockIdx.x * 16 + threadIdx.x / 16;
    int l = threadIdx.x & 15;
    if (v >= n) return;
    int lo = rowptr[v], hi = rowptr[v + 1];
    float a0 = 0.f, a1 = 0.f;
    for (int j = lo + l; j < hi; j += 16) {
        float2 h = __half22float2(hd0[csr_src[j]]);
        a0 += h.x; a1 += h.y;
    }
#pragma unroll
    for (int off = 8; off >= 1; off >>= 1) {
        a0 += __shfl_xor(a0, off, 16);
        a1 += __shfl_xor(a1, off, 16);
    }
    float dv = dinv[v];
    float2 hs = __half22float2(hd0[v]);
    a0 = (a0 + hs.x) * dv;
    a1 = (a1 + hs.y) * dv;
    float o = bg[l] + a0 * sW[l] + a1 * sW[16 + l];   // W is (2,16) row-major
    hd1[v * 16 + l] = __float2half(fmaxf(o, 0.f) * dv);
}

__device__ __forceinline__ void add8B(const __half* p, float4& acc) {
    uint2 u = *reinterpret_cast<const uint2*>(p);
    float2 fa = __half22float2(*reinterpret_cast<__half2*>(&u.x));
    float2 fb = __half22float2(*reinterpret_cast<__half2*>(&u.y));
    acc.x += fa.x; acc.y += fa.y; acc.z += fb.x; acc.w += fb.y;
}

// DIN=32: wave per node; 8 lanes x 8B per row; 8 edge slots x 2 batches = 16 in flight.
template <int DOUT, bool RELU>
__global__ __launch_bounds__(256) void k_layer32(
    const int* __restrict__ rowptr, const int* __restrict__ csr_src,
    const __half* __restrict__ hd_in, const float* __restrict__ Wg,
    const float* __restrict__ bg, const float* __restrict__ dinv,
    __half* __restrict__ hout, int n) {
    __shared__ float sW[32 * DOUT];
    for (int i = threadIdx.x; i < 32 * DOUT; i += 256) sW[i] = Wg[i];
    __syncthreads();
    int v = blockIdx.x * 4 + (threadIdx.x >> 6);
    int lane = threadIdx.x & 63;
    int q = lane & 7;          // 8B slice: features 4q..4q+3
    int el = lane >> 3;        // edge slot 0..7
    if (v >= n) return;
    int lo = rowptr[v], hi = rowptr[v + 1];
    float4 acc = {0.f, 0.f, 0.f, 0.f};
    for (int jb = lo; jb < hi; jb += 16) {
        int j0 = jb + el, j1 = jb + 8 + el;
        if (j0 < hi) add8B(hd_in + (size_t)csr_src[j0] * 32 + q * 4, acc);
        if (j1 < hi) add8B(hd_in + (size_t)csr_src[j1] * 32 + q * 4, acc);
    }
    if (el == 0) add8B(hd_in + (size_t)v * 32 + q * 4, acc);  // self loop
#pragma unroll
    for (int off = 8; off <= 32; off <<= 1) {
        acc.x += __shfl_xor(acc.x, off, 64);
        acc.y += __shfl_xor(acc.y, off, 64);
        acc.z += __shfl_xor(acc.z, off, 64);
        acc.w += __shfl_xor(acc.w, off, 64);
    }
    float dv = dinv[v];
    acc.x *= dv; acc.y *= dv; acc.z *= dv; acc.w *= dv;
    int g = lane % DOUT;
    float o = bg[g];
#pragma unroll
    for (int f2 = 0; f2 < 32; ++f2) {
        float comp = (f2 & 3) == 0 ? acc.x : (f2 & 3) == 1 ? acc.y : (f2 & 3) == 2 ? acc.z : acc.w;
        float hf = __shfl(comp, f2 >> 2, 8);
        o = fmaf(hf, sW[f2 * DOUT + g], o);
    }
    if (lane < DOUT) {
        if (RELU) o = fmaxf(o, 0.f);
        hout[(size_t)v * DOUT + g] = __float2half(o * dv);
    }
}

// DIN=16: wave per node; 4 lanes x 8B per row; 16 edge slots in flight.
template <int DOUT, bool RELU, bool LAST>
__global__ __launch_bounds__(256) void k_layer16(
    const int* __restrict__ rowptr, const int* __restrict__ csr_src,
    const __half* __restrict__ hd_in, const float* __restrict__ Wg,
    const float* __restrict__ bg, const float* __restrict__ dinv,
    const float* __restrict__ xorig, __half* __restrict__ hout_h,
    float* __restrict__ hout_f, int n) {
    __shared__ float sW[16 * DOUT];
    for (int i = threadIdx.x; i < 16 * DOUT; i += 256) sW[i] = Wg[i];
    __syncthreads();
    int v = blockIdx.x * 4 + (threadIdx.x >> 6);
    int lane = threadIdx.x & 63;
    int q = lane & 3;          // 8B slice: features 4q..4q+3
    int el = lane >> 2;        // edge slot 0..15
    if (v >= n) return;
    int lo = rowptr[v], hi = rowptr[v + 1];
    float4 acc = {0.f, 0.f, 0.f, 0.f};
    for (int jb = lo; jb < hi; jb += 16) {
        int j0 = jb + el;
        if (j0 < hi) add8B(hd_in + (size_t)csr_src[j0] * 16 + q * 4, acc);
    }
    if (el == 0) add8B(hd_in + (size_t)v * 16 + q * 4, acc);  // self loop
#pragma unroll
    for (int off = 4; off <= 32; off <<= 1) {
        acc.x += __shfl_xor(acc.x, off, 64);
        acc.y += __shfl_xor(acc.y, off, 64);
        acc.z += __shfl_xor(acc.z, off, 64);
        acc.w += __shfl_xor(acc.w, off, 64);
    }
    float dv = dinv[v];
    acc.x *= dv; acc.y *= dv; acc.z *= dv; acc.w *= dv;
    int g = lane % DOUT;
    float o = bg[g];
#pragma unroll
    for (int f2 = 0; f2 < 16; ++f2) {
        float comp = (f2 & 3) == 0 ? acc.x : (f2 & 3) == 1 ? acc.y : (f2 & 3) == 2 ? acc.z : acc.w;
        float hf = __shfl(comp, f2 >> 2, 4);
        o = fmaf(hf, sW[f2 * DOUT + g], o);
    }
    if (lane < DOUT) {
        if (LAST) {
            hout_f[(size_t)v * DOUT + g] = o + xorig[(size_t)v * 2 + g];
        } else {
            if (RELU) o = fmaxf(o, 0.f);
            hout_h[(size_t)v * DOUT + g] = __float2half(o * dv);
        }
    }
}

// ---------------- launch ----------------

extern "C" void kernel_launch(void* const* d_in, const int* in_sizes, int n_in,
                              void* d_out, int out_size, void* d_ws, size_t ws_size,
                              hipStream_t stream) {
    const float* x = (const float*)d_in[0];
    const int* ei = (const int*)d_in[1];  // int32 (harness converts integer inputs)
    const float* W[8];
    const float* B[8];
    for (int i = 0; i < 8; ++i) {
        W[i] = (const float*)d_in[2 + 2 * i];
        B[i] = (const float*)d_in[3 + 2 * i];
    }
    float* out = (float*)d_out;

    char* ws = (char*)d_ws;
    int*       deg     = (int*)      (ws + 0);          //  0.4 MB
    float*     dinv    = (float*)    (ws + 400128);     //  0.4 MB
    int*       rowptr  = (int*)      (ws + 800256);     //  0.4 MB (n+1)
    int*       exc     = (int*)      (ws + 1200384);    //  0.4 MB
    int*       bsum    = (int*)      (ws + 1600512);    //  tiny
    int*       bcur    = (int*)      (ws + 1601024);    //  tiny
    long long* pairs   = (long long*)(ws + 1601536);    // 14.45 MB
    int*       csr_src = (int*)      (ws + 16052224);   //  6.4 MB
    __half*    hdA     = (__half*)   (ws + 22452224);   //  6.4 MB
    __half*    hdB     = (__half*)   (ws + 28852224);   //  6.4 MB  (total ~35.3 MB)

    dim3 blk(256);

    k_init<<<1, 128, 0, stream>>>(bcur);
    k_bucket<<<NBE, blk, 0, stream>>>(ei, bcur, pairs, NE);
    k_count2<<<NBUCK, blk, 0, stream>>>(pairs, bcur, deg);
    k_scan1<<<NBLK, SCAN_BLK, 0, stream>>>(deg, exc, bsum, NN);
    k_scan2<<<1, 128, 0, stream>>>(bsum, NBLK);
    k_scan3<<<NBLK, SCAN_BLK, 0, stream>>>(exc, bsum, deg, x, rowptr, dinv, (__half2*)hdA, NN);
    k_fill3<<<NBUCK, blk, 0, stream>>>(pairs, bcur, rowptr, csr_src);

    int g16 = (NN + 15) / 16;   // k_layer1: 16 lanes/group
    int gW  = (NN + 3) / 4;     // wave-per-node kernels: 4 nodes/block

    // L1: hdA(2) -> hdB(16)
    k_layer1<<<g16, blk, 0, stream>>>(rowptr, csr_src, (const __half2*)hdA, W[0], B[0], dinv, hdB, NN);
    // L2: hdB(16) -> hdA(32)
    k_layer16<32, true, false><<<gW, blk, 0, stream>>>(rowptr, csr_src, hdB, W[1], B[1], dinv, x, hdA, out, NN);
    // L3: hdA(32) -> hdB(32)
    k_layer32<32, true><<<gW, blk, 0, stream>>>(rowptr, csr_src, hdA, W[2], B[2], dinv, hdB, NN);
    // L4: hdB -> hdA
    k_layer32<32, true><<<gW, blk, 0, stream>>>(rowptr, csr_src, hdB, W[3], B[3], dinv, hdA, NN);
    // L5: hdA -> hdB
    k_layer32<32, true><<<gW, blk, 0, stream>>>(rowptr, csr_src, hdA, W[4], B[4], dinv, hdB, NN);
    // L6: hdB -> hdA
    k_layer32<32, true><<<gW, blk, 0, stream>>>(rowptr, csr_src, hdB, W[5], B[5], dinv, hdA, NN);
    // L7: hdA(32) -> hdB(16)
    k_layer32<16, true><<<gW, blk, 0, stream>>>(rowptr, csr_src, hdA, W[6], B[6], dinv, hdB, NN);
    // L8: hdB(16) -> out(2), +x_orig, no relu
    k_layer16<2, false, true><<<gW, blk, 0, stream>>>(rowptr, csr_src, hdB, W[7], B[7], dinv, x, hdA, out, NN);
}

// Round 9
// 395.100 us; speedup vs baseline: 1.5526x; 1.5526x over previous
//
#include <hip/hip_runtime.h>
#include <hip/hip_fp16.h>

#define NN 100000
#define NE 1600000
#define SCAN_BLK 1024
#define NBLK ((NN + SCAN_BLK - 1) / SCAN_BLK)   // 98

#define EB 3072                                  // edges per bucket-block chunk
#define NBE ((NE + EB - 1) / EB)                 // 521
#define BSH 10                                   // 1024-node buckets
#define NBUCK ((NN + 1023) >> BSH)               // 98
#define BCAP 18432                               // pairs cap/bucket (exp 16327, sd ~127)

// ---------------- structure precompute ----------------

__global__ void k_init(int* __restrict__ bcur) {
    int i = blockIdx.x * blockDim.x + threadIdx.x;
    if (i < NBUCK) bcur[i] = i * BCAP;
}

// chunk edges -> per-bucket contiguous runs of (dst,src) pairs
__global__ __launch_bounds__(256) void k_bucket(
    const int* __restrict__ ei, int* __restrict__ bcur,
    long long* __restrict__ pairs, int nE) {
    __shared__ int cnt[NBUCK];
    __shared__ int sc[NBUCK];
    __shared__ int rc[NBUCK];
    __shared__ int gbase[NBUCK];
    __shared__ int tmp[256];
    __shared__ long long st[EB];

    int base = blockIdx.x * EB;
    int lim = nE - base; if (lim > EB) lim = EB;
    int tid = threadIdx.x;

    for (int i = tid; i < NBUCK; i += 256) cnt[i] = 0;
    __syncthreads();
    for (int i = tid; i < lim; i += 256) {
        int d = ei[nE + base + i];
        atomicAdd(&cnt[d >> BSH], 1);
    }
    __syncthreads();
    {
        int v = (tid < NBUCK) ? cnt[tid] : 0;
        tmp[tid] = v;
        __syncthreads();
        for (int off = 1; off < 256; off <<= 1) {
            int add = (tid >= off) ? tmp[tid - off] : 0;
            __syncthreads();
            tmp[tid] += add;
            __syncthreads();
        }
        if (tid < NBUCK) {
            int e = tmp[tid] - v;
            sc[tid] = e;
            rc[tid] = e;
            gbase[tid] = (v > 0) ? atomicAdd(&bcur[tid], v) : 0;
        }
    }
    __syncthreads();
    for (int i = tid; i < lim; i += 256) {
        int s = ei[base + i];
        int d = ei[nE + base + i];
        int p = atomicAdd(&rc[d >> BSH], 1);
        st[p] = ((long long)d << 32) | (unsigned int)s;
    }
    __syncthreads();
    for (int i = tid; i < lim; i += 256) {
        long long pr = st[i];
        int b = (int)(pr >> 32) >> BSH;
        pairs[gbase[b] + (i - sc[b])] = pr;
    }
}

// per-bucket LDS histogram -> coalesced non-atomic deg write
__global__ __launch_bounds__(256) void k_count2(
    const long long* __restrict__ pairs, const int* __restrict__ bcur,
    int* __restrict__ deg) {
    __shared__ int cnt[1 << BSH];
    int b = blockIdx.x;
    int gb = b * BCAP;
    int m = bcur[b] - gb;
    for (int i = threadIdx.x; i < (1 << BSH); i += 256) cnt[i] = 0;
    __syncthreads();
    for (int i = threadIdx.x; i < m; i += 256) {
        int d = (int)(pairs[gb + i] >> 32);
        atomicAdd(&cnt[d & ((1 << BSH) - 1)], 1);
    }
    __syncthreads();
    int base = b << BSH;
    for (int i = threadIdx.x; i < (1 << BSH); i += 256) {
        int v = base + i;
        if (v < NN) deg[v] = cnt[i];
    }
}

// scan over PADDED degrees: pdeg = (deg+7)&~7
__global__ __launch_bounds__(SCAN_BLK) void k_scan1(
    const int* __restrict__ deg, int* __restrict__ exc, int* __restrict__ bsum, int n) {
    __shared__ int sh[SCAN_BLK];
    int tid = threadIdx.x;
    int i = blockIdx.x * SCAN_BLK + tid;
    int v = (i < n) ? ((deg[i] + 7) & ~7) : 0;
    sh[tid] = v;
    __syncthreads();
    for (int off = 1; off < SCAN_BLK; off <<= 1) {
        int add = (tid >= off) ? sh[tid - off] : 0;
        __syncthreads();
        sh[tid] += add;
        __syncthreads();
    }
    if (i < n) exc[i] = sh[tid] - v;
    if (tid == SCAN_BLK - 1) bsum[blockIdx.x] = sh[tid];
}

__global__ __launch_bounds__(128) void k_scan2(int* __restrict__ bsum, int nb) {
    __shared__ int sh[128];
    int tid = threadIdx.x;
    int v = (tid < nb) ? bsum[tid] : 0;
    sh[tid] = v;
    __syncthreads();
    for (int off = 1; off < 128; off <<= 1) {
        int add = (tid >= off) ? sh[tid - off] : 0;
        __syncthreads();
        sh[tid] += add;
        __syncthreads();
    }
    if (tid < nb) bsum[tid] = sh[tid] - v;  // exclusive
}

// rowptr (padded) + dinv + hd0 = x*dinv (fp16) + dummy row + total
__global__ __launch_bounds__(SCAN_BLK) void k_scan3(
    const int* __restrict__ exc, const int* __restrict__ bsum,
    const int* __restrict__ deg, const float* __restrict__ x,
    int* __restrict__ rowptr, float* __restrict__ dinv,
    __half2* __restrict__ hd0, int n) {
    int i = blockIdx.x * SCAN_BLK + threadIdx.x;
    if (i >= n) return;
    int r = exc[i] + bsum[blockIdx.x];
    rowptr[i] = r;
    float dv = rsqrtf((float)(deg[i] + 1));  // +1 = self loop
    dinv[i] = dv;
    hd0[i] = __floats2half2_rn(x[2 * i] * dv, x[2 * i + 1] * dv);
    if (i == n - 1) rowptr[n] = r + ((deg[i] + 7) & ~7);
    if (i == 0) hd0[n] = __floats2half2_rn(0.f, 0.f);  // dummy row (pad target)
}

// per-bucket scatter with LDS cursors; then write pad entries (src = NN dummy)
__global__ __launch_bounds__(256) void k_fill3(
    const long long* __restrict__ pairs, const int* __restrict__ bcur,
    const int* __restrict__ rowptr, int* __restrict__ csr_src) {
    __shared__ int lcur[1 << BSH];
    int b = blockIdx.x;
    int gb = b * BCAP;
    int m = bcur[b] - gb;
    int base = b << BSH;
    for (int i = threadIdx.x; i < (1 << BSH); i += 256) {
        int v = base + i;
        lcur[i] = (v < NN) ? rowptr[v] : 0;
    }
    __syncthreads();
    for (int i = threadIdx.x; i < m; i += 256) {
        long long pr = pairs[gb + i];
        int d = (int)(pr >> 32);
        int s = (int)(pr & 0xffffffffLL);
        int pos = atomicAdd(&lcur[d & ((1 << BSH) - 1)], 1);
        csr_src[pos] = s;
    }
    __syncthreads();
    for (int i = threadIdx.x; i < (1 << BSH); i += 256) {
        int v = base + i;
        if (v < NN) {
            int e = lcur[i];          // rowptr[v] + deg[v]
            int pe = rowptr[v + 1];   // padded end
            for (; e < pe; ++e) csr_src[e] = NN;
        }
    }
}

// ---------------- layer kernels ----------------
// agg[v] = dinv[v] * (sum_j hd_in[src_j] + hd_in[v]) ; o = agg@W + b
// hd_out = relu(o)*dinv (fp16)   |  LAST: out = o + xorig (fp32)
// Rows padded to x8 with dummy src NN (zero row); each layer writes its own
// zero dummy row at index n so the next layer's pads read zeros.

// L1: DIN=2, half2 rows; 16-lane edge-split + butterfly.
__global__ __launch_bounds__(256) void k_layer1(
    const int* __restrict__ rowptr, const int* __restrict__ csr_src,
    const __half2* __restrict__ hd0, const float* __restrict__ Wg,
    const float* __restrict__ bg, const float* __restrict__ dinv,
    __half* __restrict__ hd1, int n) {
    __shared__ float sW[32];
    if (threadIdx.x < 32) sW[threadIdx.x] = Wg[threadIdx.x];
    __syncthreads();
    int v = blockIdx.x * 16 + threadIdx.x / 16;
    int l = threadIdx.x & 15;
    if (v > n) return;
    if (v == n) { hd1[v * 16 + l] = __float2half(0.f); return; }  // dummy row
    int lo = rowptr[v], hi = rowptr[v + 1];
    float a0 = 0.f, a1 = 0.f;
    for (int j = lo + l; j < hi; j += 16) {
        float2 h = __half22float2(hd0[csr_src[j]]);
        a0 += h.x; a1 += h.y;
    }
#pragma unroll
    for (int off = 8; off >= 1; off >>= 1) {
        a0 += __shfl_xor(a0, off, 16);
        a1 += __shfl_xor(a1, off, 16);
    }
    float dv = dinv[v];
    float2 hs = __half22float2(hd0[v]);
    a0 = (a0 + hs.x) * dv;
    a1 = (a1 + hs.y) * dv;
    float o = bg[l] + a0 * sW[l] + a1 * sW[16 + l];   // W is (2,16) row-major
    hd1[v * 16 + l] = __float2half(fmaxf(o, 0.f) * dv);
}

// Generic layer, fp16 hd, branch-free 8-chunk gather.
template <int DIN, int DOUT, bool RELU, bool LAST, bool TWOWAY>
__global__ __launch_bounds__(256) void k_layer(
    const int* __restrict__ rowptr, const int* __restrict__ csr_src,
    const __half* __restrict__ hd_in, const float* __restrict__ Wg,
    const float* __restrict__ bg, const float* __restrict__ dinv,
    const float* __restrict__ xorig, __half* __restrict__ hout_h,
    float* __restrict__ hout_f, int n) {
    constexpr int OPL = (DOUT + DIN - 1) / DIN;
    constexpr int LPG = DIN * (TWOWAY ? 2 : 1);
    __shared__ float sW[DIN * DOUT];
    for (int i = threadIdx.x; i < DIN * DOUT; i += 256) sW[i] = Wg[i];
    __syncthreads();
    const int gpb = 256 / LPG;
    int v = blockIdx.x * gpb + (int)threadIdx.x / LPG;
    int f = threadIdx.x % DIN;
    int way = (threadIdx.x % LPG) / DIN;
    if (v > n) return;
    if (v == n) {                       // dummy row: keep zeros for next layer
        if (!LAST && way == 0) {
#pragma unroll
            for (int k = 0; k < OPL; ++k) {
                int g = f + k * DIN;
                if (g < DOUT) hout_h[v * DOUT + g] = __float2half(0.f);
            }
        }
        return;
    }
    int lo = rowptr[v], hi = rowptr[v + 1];   // (hi-lo) % 8 == 0
    if (TWOWAY) {
        int nch = (hi - lo) >> 3;
        int mid = lo + (((nch + 1) >> 1) << 3);
        if (way == 0) hi = mid; else lo = mid;
    }
    float acc = 0.f;
    for (int j = lo; j < hi; j += 8) {   // branch-free: full chunks only
        int s0 = csr_src[j + 0], s1 = csr_src[j + 1], s2 = csr_src[j + 2], s3 = csr_src[j + 3];
        int s4 = csr_src[j + 4], s5 = csr_src[j + 5], s6 = csr_src[j + 6], s7 = csr_src[j + 7];
        float v0 = __half2float(hd_in[s0 * DIN + f]);
        float v1 = __half2float(hd_in[s1 * DIN + f]);
        float v2 = __half2float(hd_in[s2 * DIN + f]);
        float v3 = __half2float(hd_in[s3 * DIN + f]);
        float v4 = __half2float(hd_in[s4 * DIN + f]);
        float v5 = __half2float(hd_in[s5 * DIN + f]);
        float v6 = __half2float(hd_in[s6 * DIN + f]);
        float v7 = __half2float(hd_in[s7 * DIN + f]);
        acc += ((v0 + v1) + (v2 + v3)) + ((v4 + v5) + (v6 + v7));
    }
    if (TWOWAY) acc += __shfl_xor(acc, DIN, 64);   // combine ways (both keep sum)
    float dv = dinv[v];
    float aggv = (acc + __half2float(hd_in[v * DIN + f])) * dv;

    if (TWOWAY) {
        // split the f2 reduction across ways, combine once at the end
        int g = f % DOUT;
        float o = (way == 0) ? bg[g] : 0.f;
        int f2b = way * (DIN / 2);
#pragma unroll
        for (int k = 0; k < DIN / 2; ++k) {
            int f2 = f2b + k;
            o = fmaf(__shfl(aggv, f2, DIN), sW[f2 * DOUT + g], o);
        }
        o += __shfl_xor(o, DIN, 64);
        if (way == 0 && f < DOUT) {
            float r = o;
            if (RELU) r = fmaxf(r, 0.f);
            if (LAST) hout_f[v * DOUT + g] = r + xorig[v * 2 + g];
            else      hout_h[v * DOUT + g] = __float2half(r * dv);
        }
    } else {
        float o[OPL];
#pragma unroll
        for (int k = 0; k < OPL; ++k) {
            int g = f + k * DIN;
            o[k] = (g < DOUT) ? bg[g] : 0.f;
        }
#pragma unroll
        for (int f2 = 0; f2 < DIN; ++f2) {
            float hf = __shfl(aggv, f2, DIN);
#pragma unroll
            for (int k = 0; k < OPL; ++k) {
                int g = f + k * DIN;
                if (g < DOUT) o[k] = fmaf(hf, sW[f2 * DOUT + g], o[k]);
            }
        }
#pragma unroll
        for (int k = 0; k < OPL; ++k) {
            int g = f + k * DIN;
            if (g < DOUT) {
                float r = o[k];
                if (RELU) r = fmaxf(r, 0.f);
                if (LAST) hout_f[v * DOUT + g] = r + xorig[v * 2 + g];
                else      hout_h[v * DOUT + g] = __float2half(r * dv);
            }
        }
    }
}

// ---------------- launch ----------------

extern "C" void kernel_launch(void* const* d_in, const int* in_sizes, int n_in,
                              void* d_out, int out_size, void* d_ws, size_t ws_size,
                              hipStream_t stream) {
    const float* x = (const float*)d_in[0];
    const int* ei = (const int*)d_in[1];  // int32 (harness converts integer inputs)
    const float* W[8];
    const float* B[8];
    for (int i = 0; i < 8; ++i) {
        W[i] = (const float*)d_in[2 + 2 * i];
        B[i] = (const float*)d_in[3 + 2 * i];
    }
    float* out = (float*)d_out;

    char* ws = (char*)d_ws;
    int*       deg     = (int*)      (ws + 0);          //  0.4 MB
    float*     dinv    = (float*)    (ws + 400128);     //  0.4 MB
    int*       rowptr  = (int*)      (ws + 800256);     //  0.4 MB (n+1)
    int*       exc     = (int*)      (ws + 1200384);    //  0.4 MB
    int*       bsum    = (int*)      (ws + 1600512);    //  tiny
    int*       bcur    = (int*)      (ws + 1601024);    //  tiny
    long long* pairs   = (long long*)(ws + 1601536);    // 14.45 MB
    int*       csr_src = (int*)      (ws + 16052224);   //  9.6 MB (padded <= NE+7*NN)
    __half*    hdA     = (__half*)   (ws + 25652224);   //  6.4 MB + dummy row
    __half*    hdB     = (__half*)   (ws + 32052352);   //  6.4 MB + dummy row (total ~38.5 MB)

    dim3 blk(256);

    k_init<<<1, 128, 0, stream>>>(bcur);
    k_bucket<<<NBE, blk, 0, stream>>>(ei, bcur, pairs, NE);
    k_count2<<<NBUCK, blk, 0, stream>>>(pairs, bcur, deg);
    k_scan1<<<NBLK, SCAN_BLK, 0, stream>>>(deg, exc, bsum, NN);
    k_scan2<<<1, 128, 0, stream>>>(bsum, NBLK);
    k_scan3<<<NBLK, SCAN_BLK, 0, stream>>>(exc, bsum, deg, x, rowptr, dinv, (__half2*)hdA, NN);
    k_fill3<<<NBUCK, blk, 0, stream>>>(pairs, bcur, rowptr, csr_src);

    int g16 = (NN + 16) / 16;   // 16 nodes/block (+1 dummy)
    int gT  = (NN + 4) / 4;     // TWOWAY: 4 nodes/block (+1 dummy)

    // L1: hdA(2) -> hdB(16)
    k_layer1<<<g16, blk, 0, stream>>>(rowptr, csr_src, (const __half2*)hdA, W[0], B[0], dinv, hdB, NN);
    // L2: hdB(16) -> hdA(32)
    k_layer<16, 32, true, false, false><<<g16, blk, 0, stream>>>(rowptr, csr_src, hdB, W[1], B[1], dinv, x, hdA, out, NN);
    // L3: hdA(32) -> hdB(32)
    k_layer<32, 32, true, false, true><<<gT, blk, 0, stream>>>(rowptr, csr_src, hdA, W[2], B[2], dinv, x, hdB, out, NN);
    // L4: hdB -> hdA
    k_layer<32, 32, true, false, true><<<gT, blk, 0, stream>>>(rowptr, csr_src, hdB, W[3], B[3], dinv, x, hdA, out, NN);
    // L5: hdA -> hdB
    k_layer<32, 32, true, false, true><<<gT, blk, 0, stream>>>(rowptr, csr_src, hdA, W[4], B[4], dinv, x, hdB, out, NN);
    // L6: hdB -> hdA
    k_layer<32, 32, true, false, true><<<gT, blk, 0, stream>>>(rowptr, csr_src, hdB, W[5], B[5], dinv, x, hdA, out, NN);
    // L7: hdA(32) -> hdB(16)
    k_layer<32, 16, true, false, true><<<gT, blk, 0, stream>>>(rowptr, csr_src, hdA, W[6], B[6], dinv, x, hdB, out, NN);
    // L8: hdB(16) -> out(2), +x_orig, no relu
    k_layer<16, 2, false, true, false><<<g16, blk, 0, stream>>>(rowptr, csr_src, hdB, W[7], B[7], dinv, x, hdA, out, NN);
}